// Round 13
// baseline (382.950 us; speedup 1.0000x reference)
//
#include <hip/hip_runtime.h>
#include <math.h>

#define L_TOKN 13294
#define BATCHN 4
#define NTOK (BATCHN * L_TOKN)     // 53176
#define NTOKP 53248                // padded: multiple of 128 (and 64)
#define DMODEL 256
#define DFFN 1024

typedef __attribute__((ext_vector_type(8))) short short8;
typedef __attribute__((ext_vector_type(4))) float f32x4;
typedef __attribute__((ext_vector_type(2))) float f32x2;

__device__ __forceinline__ ushort f2b(float f) {
    uint u = __float_as_uint(f);
    u += 0x7fff + ((u >> 16) & 1);
    return (ushort)(u >> 16);
}
__device__ __forceinline__ float b2f(uint h) {
    return __uint_as_float(h << 16);
}

// ---------------------------------------------------------------------------
// prep: [0, 2*n4)  addcvt (qb = bf16(src+pos), memb = bf16(src2+mpos))
//       [2*n4, +753664) weight transpose/convert W[K][N] f32 -> Wt[N][K] bf16
// ---------------------------------------------------------------------------
__global__ __launch_bounds__(256) void prep_k(
    const float* __restrict__ s1, const float* __restrict__ p1,
    const float* __restrict__ s2, const float* __restrict__ p2,
    ushort* __restrict__ o1, ushort* __restrict__ o2,
    const float* __restrict__ w0, const float* __restrict__ w1,
    const float* __restrict__ w2, const float* __restrict__ w3,
    const float* __restrict__ w4, const float* __restrict__ w5,
    ushort* __restrict__ wtb, int n4)
{
    int i = blockIdx.x * 256 + threadIdx.x;
    if (i < 2 * n4) {
        const float* a; const float* b; ushort* o; int j;
        if (i < n4) { a = s1; b = p1; o = o1; j = i; }
        else        { a = s2; b = p2; o = o2; j = i - n4; }
        float4 va = ((const float4*)a)[j];
        float4 vb = ((const float4*)b)[j];
        ushort4 r;
        r.x = f2b(va.x + vb.x); r.y = f2b(va.y + vb.y);
        r.z = f2b(va.z + vb.z); r.w = f2b(va.w + vb.w);
        ((ushort4*)o)[j] = r;
        return;
    }
    int i2 = i - 2 * n4;
    const float* w; int Nd; size_t off; int j;
    if      (i2 < 65536)  { w = w0; Nd = 256;  off = 0;      j = i2; }
    else if (i2 < 131072) { w = w1; Nd = 256;  off = 65536;  j = i2 - 65536; }
    else if (i2 < 163840) { w = w2; Nd = 128;  off = 131072; j = i2 - 131072; }
    else if (i2 < 229376) { w = w3; Nd = 256;  off = 163840; j = i2 - 163840; }
    else if (i2 < 491520) { w = w4; Nd = 1024; off = 229376; j = i2 - 229376; }
    else if (i2 < 753664) { w = w5; Nd = 256;  off = 491520; j = i2 - 491520; }
    else return;
    int Kd = (i2 < 491520) ? 256 : 1024;
    int k = j / Nd, n = j - k * Nd;
    wtb[off + (size_t)n * Kd + k] = f2b(w[j]);
}

// ---------------------------------------------------------------------------
// bf16 MFMA GEMM core, 64x128 tile, BK=32, global_load_lds double-buffered,
// counted vmcnt(3). 24KB LDS -> ~6 blocks/CU. acc[4][2] per wave.
// A rows padded to 64-multiple. Wt[N][K]. NOT safe in-place.
// ---------------------------------------------------------------------------
__device__ __forceinline__ void gemm_core(
    const ushort* __restrict__ A, const ushort* __restrict__ Wt,
    const float* __restrict__ bias, const float* __restrict__ bias2,
    float* __restrict__ Cf, ushort* __restrict__ Cb,
    int M, int N, int K, int relu, int nsplit, int m0, int n0)
{
    __shared__ ushort lds[12288];   // 2 x (A 64x32 + B 128x32) = 24KB

    const int t  = threadIdx.x;
    const int wv = t >> 6, ln_ = t & 63;
    const int fr = ln_ & 15;
    const int kg = ln_ >> 4;

    f32x4 acc[4][2];
    #pragma unroll
    for (int i = 0; i < 4; i++)
        #pragma unroll
        for (int j = 0; j < 2; j++) acc[i][j] = (f32x4)0.0f;

    int aoff[4], boff[2];
    #pragma unroll
    for (int i = 0; i < 4; i++)
        aoff[i] = (i * 16 + fr) * 32 + kg * 8;
    #pragma unroll
    for (int j = 0; j < 2; j++)
        boff[j] = 2048 + (wv * 32 + j * 16 + fr) * 32 + kg * 8;

// 3 loads/thread per STAGE (1 A + 2 B); vmcnt accounting relies on this.
#define STAGE(pbuf, k0) do {                                                       \
    {   /* A: 256 chunks, 1/lane */                                                \
        int c = wv * 64 + ln_;                                                     \
        int m = c >> 2, s = c & 3;                                                 \
        const ushort* sa = A + (size_t)(m0 + m) * K + (k0) + s * 8;                \
        __builtin_amdgcn_global_load_lds(                                          \
            (const __attribute__((address_space(1))) unsigned int*)sa,             \
            (__attribute__((address_space(3))) unsigned int*)&lds[(pbuf) * 6144 + wv * 512], \
            16, 0, 0);                                                             \
    }                                                                              \
    _Pragma("unroll")                                                              \
    for (int ii = 0; ii < 2; ii++) {   /* B: 512 chunks, 2/lane */                 \
        int c = wv * 128 + ii * 64 + ln_;                                          \
        int n = c >> 2, s = c & 3;                                                 \
        const ushort* sb = Wt + (size_t)(n0 + n) * K + (k0) + s * 8;               \
        __builtin_amdgcn_global_load_lds(                                          \
            (const __attribute__((address_space(1))) unsigned int*)sb,             \
            (__attribute__((address_space(3))) unsigned int*)&lds[(pbuf) * 6144 + 2048 + wv * 1024 + ii * 512], \
            16, 0, 0);                                                             \
    }                                                                              \
} while (0)

    const int nk = K >> 5;
    STAGE(0, 0);
    if (nk > 1) STAGE(1, 32);

    for (int ks = 0; ks < nk; ks++) {
        const int p = ks & 1;
        if (ks + 1 < nk) {
            asm volatile("s_waitcnt vmcnt(3)" ::: "memory");
        } else {
            asm volatile("s_waitcnt vmcnt(0)" ::: "memory");
        }
        __builtin_amdgcn_s_barrier();
        __builtin_amdgcn_sched_barrier(0);

        short8 af[4], bf[2];
        const int pb = p * 6144;
        #pragma unroll
        for (int i = 0; i < 4; i++)
            af[i] = *(const short8*)&lds[pb + aoff[i]];
        #pragma unroll
        for (int j = 0; j < 2; j++)
            bf[j] = *(const short8*)&lds[pb + boff[j]];

        if (ks + 2 < nk) {
            asm volatile("s_waitcnt lgkmcnt(0)" ::: "memory");
            __builtin_amdgcn_s_barrier();
            __builtin_amdgcn_sched_barrier(0);
            STAGE(p, (ks + 2) << 5);
        }
        #pragma unroll
        for (int i = 0; i < 4; i++)
            #pragma unroll
            for (int j = 0; j < 2; j++)
                acc[i][j] = __builtin_amdgcn_mfma_f32_16x16x32_bf16(af[i], bf[j], acc[i][j], 0, 0, 0);
    }
#undef STAGE

    #pragma unroll
    for (int i = 0; i < 4; i++) {
        #pragma unroll
        for (int j = 0; j < 2; j++) {
            int col = n0 + wv * 32 + j * 16 + fr;
            float bv = (col < nsplit) ? bias[col] : bias2[col - nsplit];
            #pragma unroll
            for (int e = 0; e < 4; e++) {
                int row = m0 + i * 16 + kg * 4 + e;
                if (row >= M) continue;
                float v = acc[i][j][e] + bv;
                if (relu) v = fmaxf(v, 0.f);
                if (Cf) Cf[(size_t)row * N + col] = v;
                if (Cb) Cb[(size_t)row * N + col] = f2b(v);
            }
        }
    }
}

// bijective XCD swizzle (m204): contiguous tile band per XCD (total % 8 == 0).
__device__ __forceinline__ int2 xcd_tile(int nx)
{
    int flat  = blockIdx.x + blockIdx.y * gridDim.x;
    int total = gridDim.x * gridDim.y;
    int tile;
    if (total & 7) tile = flat;
    else           tile = (flat & 7) * (total >> 3) + (flat >> 3);
    int2 r; r.x = tile % nx; r.y = tile / nx;
    return r;
}

// generic GEMM: n-tile on x (L2 A-reuse), m-strip(64) on y, XCD-swizzled
__global__ __launch_bounds__(256) void mgemm_k(
    const ushort* __restrict__ A, const ushort* __restrict__ Wt,
    const float* __restrict__ bias, const float* __restrict__ bias2,
    float* __restrict__ Cf, ushort* __restrict__ Cb,
    int M, int N, int K, int relu, int nsplit)
{
    int2 xy = xcd_tile(gridDim.x);
    gemm_core(A, Wt, bias, bias2, Cf, Cb, M, N, K, relu, nsplit,
              xy.y * 64, xy.x * 128);
}

// merged value-proj (x<2) + offaw-proj (x>=2), both K=256
__global__ __launch_bounds__(256) void projs_k(
    const ushort* __restrict__ memb, const ushort* __restrict__ qb,
    const ushort* __restrict__ value_wt, const ushort* __restrict__ offaw_wt,
    const float* __restrict__ value_b, const float* __restrict__ off_b,
    const float* __restrict__ aw_b,
    ushort* __restrict__ vb, ushort* __restrict__ offawb)
{
    int2 xy = xcd_tile(5);
    const int x = xy.x;
    const int m0 = xy.y * 64;
    if (x < 2)
        gemm_core(memb, value_wt, value_b, value_b, nullptr, vb,
                  NTOK, 256, 256, 0, 256, m0, x * 128);
    else
        gemm_core(qb, offaw_wt, off_b, aw_b, nullptr, offawb,
                  NTOK, 384, 256, 0, 256, m0, (x - 2) * 128);
}

// ---------------------------------------------------------------------------
// GEMM + fused residual + LayerNorm epilogue. 64x256 tile (FULL output row),
// BK=32, counted vmcnt(5), 40KB LDS. Wave wv owns cols [wv*64, wv*64+64),
// acc[4][4]. Epilogue: v = acc + bias + residual (f32); row-reduce via
// 16-lane shfl + cross-wave LDS partials (reuses buf0 staging region, which
// the final K-step never reads: nk even -> last reads hit buf1).
// Output: LN(v) to outf f32 and/or outb bf16. N fixed = 256.
// ---------------------------------------------------------------------------
__global__ __launch_bounds__(256) void gemm_ln_k(
    const ushort* __restrict__ A, const ushort* __restrict__ Wt,
    const float* __restrict__ bias,
    const float* __restrict__ resf, const ushort* __restrict__ resb,
    const float* __restrict__ lng, const float* __restrict__ lnbta,
    float* __restrict__ outf, ushort* __restrict__ outb, int K)
{
    __shared__ ushort lds[20480];   // 2 x (A 2048 + B 8192) = 40KB

    const int t  = threadIdx.x;
    const int wv = t >> 6, ln_ = t & 63;
    const int fr = ln_ & 15;
    const int kg = ln_ >> 4;

    // bijective XCD swizzle over 832 m-strips (832 % 8 == 0)
    const int flat = blockIdx.x, total = gridDim.x;
    const int m0 = ((total & 7) ? flat
                                : ((flat & 7) * (total >> 3) + (flat >> 3))) * 64;

    f32x4 acc[4][4];
    #pragma unroll
    for (int i = 0; i < 4; i++)
        #pragma unroll
        for (int j = 0; j < 4; j++) acc[i][j] = (f32x4)0.0f;

    int aoff[4], boff[4];
    #pragma unroll
    for (int i = 0; i < 4; i++)
        aoff[i] = (i * 16 + fr) * 32 + kg * 8;
    #pragma unroll
    for (int j = 0; j < 4; j++)
        boff[j] = 2048 + (wv * 64 + j * 16 + fr) * 32 + kg * 8;

// 5 loads/thread per STAGE (1 A + 4 B); vmcnt(5) accounting relies on this.
#define STAGE2(pbuf, k0) do {                                                      \
    {   /* A: 256 chunks, 1/lane */                                                \
        int c = wv * 64 + ln_;                                                     \
        int m = c >> 2, s = c & 3;                                                 \
        const ushort* sa = A + (size_t)(m0 + m) * K + (k0) + s * 8;                \
        __builtin_amdgcn_global_load_lds(                                          \
            (const __attribute__((address_space(1))) unsigned int*)sa,             \
            (__attribute__((address_space(3))) unsigned int*)&lds[(pbuf) * 10240 + wv * 512], \
            16, 0, 0);                                                             \
    }                                                                              \
    _Pragma("unroll")                                                              \
    for (int ii = 0; ii < 4; ii++) {   /* B: 1024 chunks, 4/lane */                \
        int c = wv * 256 + ii * 64 + ln_;                                          \
        int n = c >> 2, s = c & 3;                                                 \
        const ushort* sb = Wt + (size_t)n * K + (k0) + s * 8;                      \
        __builtin_amdgcn_global_load_lds(                                          \
            (const __attribute__((address_space(1))) unsigned int*)sb,             \
            (__attribute__((address_space(3))) unsigned int*)&lds[(pbuf) * 10240 + 2048 + wv * 2048 + ii * 512], \
            16, 0, 0);                                                             \
    }                                                                              \
} while (0)

    const int nk = K >> 5;   // 8 or 32 (always even)
    STAGE2(0, 0);
    STAGE2(1, 32);

    for (int ks = 0; ks < nk; ks++) {
        const int p = ks & 1;
        if (ks + 1 < nk) {
            asm volatile("s_waitcnt vmcnt(5)" ::: "memory");
        } else {
            asm volatile("s_waitcnt vmcnt(0)" ::: "memory");
        }
        __builtin_amdgcn_s_barrier();
        __builtin_amdgcn_sched_barrier(0);

        short8 af[4], bf[4];
        const int pb = p * 10240;
        #pragma unroll
        for (int i = 0; i < 4; i++)
            af[i] = *(const short8*)&lds[pb + aoff[i]];
        #pragma unroll
        for (int j = 0; j < 4; j++)
            bf[j] = *(const short8*)&lds[pb + boff[j]];

        if (ks + 2 < nk) {
            asm volatile("s_waitcnt lgkmcnt(0)" ::: "memory");
            __builtin_amdgcn_s_barrier();
            __builtin_amdgcn_sched_barrier(0);
            STAGE2(p, (ks + 2) << 5);
        }
        #pragma unroll
        for (int i = 0; i < 4; i++)
            #pragma unroll
            for (int j = 0; j < 4; j++)
                acc[i][j] = __builtin_amdgcn_mfma_f32_16x16x32_bf16(af[i], bf[j], acc[i][j], 0, 0, 0);
    }
#undef STAGE2

    // ---- epilogue: bias + residual (f32), then LN per row over 256 cols ----
    #pragma unroll
    for (int i = 0; i < 4; i++) {
        #pragma unroll
        for (int j = 0; j < 4; j++) {
            int col = wv * 64 + j * 16 + fr;
            float bv = bias[col];
            #pragma unroll
            for (int e = 0; e < 4; e++) {
                size_t idx = (size_t)(m0 + i * 16 + kg * 4 + e) * 256 + col;
                float r = resf ? resf[idx] : b2f((uint)resb[idx]);
                acc[i][j][e] += bv + r;
            }
        }
    }

    // per-thread row partials over this wave's 64 cols (4 j-elements each)
    float s1[16], s2[16];
    #pragma unroll
    for (int i = 0; i < 4; i++)
        #pragma unroll
        for (int e = 0; e < 4; e++) {
            float a = acc[i][0][e], b = acc[i][1][e];
            float c = acc[i][2][e], d = acc[i][3][e];
            s1[i * 4 + e] = a + b + c + d;
            s2[i * 4 + e] = a * a + b * b + c * c + d * d;
        }
    #pragma unroll
    for (int o = 8; o; o >>= 1) {
        #pragma unroll
        for (int r = 0; r < 16; r++) {
            s1[r] += __shfl_xor(s1[r], o);
            s2[r] += __shfl_xor(s2[r], o);
        }
    }

    // cross-wave reduction via LDS (buf0 A-region, 2KB needed, unused now)
    float* sumS = (float*)lds;          // [4][64]
    float* sqS  = (float*)lds + 256;    // [4][64]
    __syncthreads();                     // all waves past final ds_reads
    if (fr == 0) {
        #pragma unroll
        for (int i = 0; i < 4; i++)
            #pragma unroll
            for (int e = 0; e < 4; e++) {
                int r = i * 16 + kg * 4 + e;
                sumS[wv * 64 + r] = s1[i * 4 + e];
                sqS[wv * 64 + r]  = s2[i * 4 + e];
            }
    }
    __syncthreads();

    #pragma unroll
    for (int i = 0; i < 4; i++) {
        #pragma unroll
        for (int e = 0; e < 4; e++) {
            int r = i * 16 + kg * 4 + e;
            float tS = sumS[r] + sumS[64 + r] + sumS[128 + r] + sumS[192 + r];
            float tQ = sqS[r]  + sqS[64 + r]  + sqS[128 + r]  + sqS[192 + r];
            float mu = tS * (1.f / 256.f);
            float var = tQ * (1.f / 256.f) - mu * mu;
            float rstd = rsqrtf(var + 1e-5f);
            int row = m0 + i * 16 + kg * 4 + e;
            if (row >= NTOK) continue;
            #pragma unroll
            for (int j = 0; j < 4; j++) {
                int col = wv * 64 + j * 16 + fr;
                float o = (acc[i][j][e] - mu) * rstd * lng[col] + lnbta[col];
                if (outf) outf[(size_t)row * 256 + col] = o;
                if (outb) outb[(size_t)row * 256 + col] = f2b(o);
            }
        }
    }
}

// ---------------------------------------------------------------------------
// Deformable attention v5 (unchanged from round 12).
// ---------------------------------------------------------------------------
__global__ __launch_bounds__(256) void deform_k(
    const ushort* __restrict__ Vb,      // bf16 (NTOK,256)
    const ushort* __restrict__ OFFAW,   // bf16 (NTOK,384)
    ushort* __restrict__ OUTb)          // bf16 (NTOK,256)
{
    __shared__ uint4 pw_s[4][2][136];   // 17408 B

    const int t = threadIdx.x;
    const int wv = t >> 6, lane = t & 63;
    const int tok0 = blockIdx.x * 8 + wv * 2;

    const int HWc[4] = {100, 50, 25, 13};
    const int STc[4] = {0, 10000, 12500, 13125};

    const int ppb = lane & 15;
    const int lvb = ppb >> 2;
    #pragma unroll
    for (int it = 0; it < 4; it++) {
        int tk = it >> 1;
        int h  = ((it & 1) << 2) + (lane >> 4);
        int row = tok0 + tk;
        int b = row / L_TOKN;
        int l = row - b * L_TOKN;
        int st_q, Wq;
        if      (l < 10000) { st_q = 0;     Wq = 100; }
        else if (l < 12500) { st_q = 10000; Wq = 50;  }
        else if (l < 13125) { st_q = 12500; Wq = 25;  }
        else                { st_q = 13125; Wq = 13;  }
        int li = l - st_q;
        int rowi = li / Wq;
        int coli = li - rowi * Wq;
        float rx = (coli + 0.5f) / (float)Wq;
        float ry = (rowi + 0.5f) / (float)Wq;

        const size_t rbase = (size_t)row * 384;
        uint oxy = *(const uint*)(OFFAW + rbase + h * 32 + ppb * 2);
        float ox = b2f(oxy & 0xffffu);
        float oy = b2f(oxy >> 16);
        float lg = b2f((uint)OFFAW[rbase + 256 + h * 16 + ppb]);
        float mx = lg;
        #pragma unroll
        for (int o = 8; o; o >>= 1) mx = fmaxf(mx, __shfl_xor(mx, o));
        float ex = __expf(lg - mx);
        float sm = ex;
        #pragma unroll
        for (int o = 8; o; o >>= 1) sm += __shfl_xor(sm, o);
        float aw = ex / sm;

        int Wl = HWc[lvb], stl = STc[lvb];
        float Wlf = (float)Wl;
        float x = (rx + ox / Wlf) * Wlf - 0.5f;
        float y = (ry + oy / Wlf) * Wlf - 0.5f;
        float x0f = floorf(x), y0f = floorf(y);
        float wx1 = x - x0f, wy1 = y - y0f;
        float wx0 = 1.f - wx1, wy0 = 1.f - wy1;
        int x0 = (int)x0f, y0 = (int)y0f;
        bool vx0 = (x0 >= 0) & (x0 < Wl);
        bool vx1 = (x0 + 1 >= 0) & (x0 + 1 < Wl);
        bool vy0 = (y0 >= 0) & (y0 < Wl);
        bool vy1 = (y0 + 1 >= 0) & (y0 + 1 < Wl);
        int cx0 = min(max(x0, 0), Wl - 1), cx1 = min(max(x0 + 1, 0), Wl - 1);
        int cy0 = min(max(y0, 0), Wl - 1), cy1 = min(max(y0 + 1, 0), Wl - 1);
        uint gb = (uint)(b * L_TOKN + stl);
        uint i00 = gb + cy0 * Wl + cx0;
        uint i10 = gb + cy0 * Wl + cx1;
        uint i01 = gb + cy1 * Wl + cx0;
        uint i11 = gb + cy1 * Wl + cx1;
        float w00 = wx0 * wy0 * aw * (float)(vx0 & vy0);
        float w10 = wx1 * wy0 * aw * (float)(vx1 & vy0);
        float w01 = wx0 * wy1 * aw * (float)(vx0 & vy1);
        float w11 = wx1 * wy1 * aw * (float)(vx1 & vy1);
        uint4 pk;
        pk.x = (int)(i00 | (i10 << 16));
        pk.y = (int)(i01 | (i11 << 16));
        pk.z = (int)((uint)f2b(w00) | ((uint)f2b(w10) << 16));
        pk.w = (int)((uint)f2b(w01) | ((uint)f2b(w11) << 16));
        pw_s[wv][tk][h * 17 + ppb] = pk;
    }

    asm volatile("s_waitcnt lgkmcnt(0)" ::: "memory");
    __builtin_amdgcn_sched_barrier(0);

    const int tk = lane >> 5;
    const int h  = (lane >> 2) & 7;
    const int dq = lane & 3;
    const int row = tok0 + tk;
    const uint choff = (uint)(h * 64 + dq * 16);
    const char* __restrict__ vbase = (const char*)Vb;

    f32x2 acc2[4];
    #pragma unroll
    for (int k = 0; k < 4; k++) acc2[k] = (f32x2)0.0f;

    #pragma unroll 8
    for (int pq = 0; pq < 16; pq++) {
        uint4 pk = pw_s[wv][tk][h * 17 + pq];
        float w00 = b2f((uint)pk.z & 0xffffu);
        float w10 = __uint_as_float((uint)pk.z & 0xffff0000u);
        float w01 = b2f((uint)pk.w & 0xffffu);
        float w11 = __uint_as_float((uint)pk.w & 0xffff0000u);
        uint a00 = (((uint)pk.x & 0xffffu) << 9) + choff;
        uint a10 = (((uint)pk.x >> 16) << 9) + choff;
        uint a01 = (((uint)pk.y & 0xffffu) << 9) + choff;
        uint a11 = (((uint)pk.y >> 16) << 9) + choff;
        uint4 v00 = *(const uint4*)(vbase + a00);
        uint4 v10 = *(const uint4*)(vbase + a10);
        uint4 v01 = *(const uint4*)(vbase + a01);
        uint4 v11 = *(const uint4*)(vbase + a11);
        const uint* p00 = (const uint*)&v00;
        const uint* p10 = (const uint*)&v10;
        const uint* p01 = (const uint*)&v01;
        const uint* p11 = (const uint*)&v11;
        #pragma unroll
        for (int k = 0; k < 4; k++) {
            f32x2 a0, a1, a2, a3;
            a0.x = __uint_as_float(p00[k] << 16); a0.y = __uint_as_float(p00[k] & 0xffff0000u);
            a1.x = __uint_as_float(p10[k] << 16); a1.y = __uint_as_float(p10[k] & 0xffff0000u);
            a2.x = __uint_as_float(p01[k] << 16); a2.y = __uint_as_float(p01[k] & 0xffff0000u);
            a3.x = __uint_as_float(p11[k] << 16); a3.y = __uint_as_float(p11[k] & 0xffff0000u);
            acc2[k] += a0 * w00 + a1 * w10 + a2 * w01 + a3 * w11;
        }
    }
    ushort4 olo, ohi;
    olo.x = f2b(acc2[0].x); olo.y = f2b(acc2[0].y);
    olo.z = f2b(acc2[1].x); olo.w = f2b(acc2[1].y);
    ohi.x = f2b(acc2[2].x); ohi.y = f2b(acc2[2].y);
    ohi.z = f2b(acc2[3].x); ohi.w = f2b(acc2[3].y);
    ushort* op = OUTb + (size_t)row * 256 + h * 32 + dq * 8;
    *(ushort4*)op = olo;
    *(ushort4*)(op + 4) = ohi;
}

// ---------------------------------------------------------------------------
extern "C" void kernel_launch(void* const* d_in, const int* in_sizes, int n_in,
                              void* d_out, int out_size, void* d_ws, size_t ws_size,
                              hipStream_t stream)
{
    const float* src     = (const float*)d_in[0];
    const float* src2    = (const float*)d_in[1];
    const float* pos     = (const float*)d_in[2];
    const float* mpos    = (const float*)d_in[3];
    const float* value_w = (const float*)d_in[4];
    const float* value_b = (const float*)d_in[5];
    const float* off_w   = (const float*)d_in[6];
    const float* off_b   = (const float*)d_in[7];
    const float* aw_w    = (const float*)d_in[8];
    const float* aw_b    = (const float*)d_in[9];
    const float* out_w   = (const float*)d_in[10];
    const float* out_b   = (const float*)d_in[11];
    const float* ln_g    = (const float*)d_in[12];
    const float* ln_b    = (const float*)d_in[13];
    const float* lin1_w  = (const float*)d_in[14];
    const float* lin1_b  = (const float*)d_in[15];
    const float* lin2_w  = (const float*)d_in[16];
    const float* lin2_b  = (const float*)d_in[17];

    float* outp = (float*)d_out;
    char*  w8   = (char*)d_ws;

    // layout (bytes): wtb | offawb | qb | vb | pad | memb | attb
    // FFN hidden (109,051,904) overlays offawb+qb+vb+pad exactly.
    const size_t SLAB = (size_t)NTOKP * 256 * 2;            // 27,262,976
    const size_t OASZ = (size_t)NTOKP * 384 * 2;            // 40,894,464
    const size_t HSZ  = (size_t)NTOKP * 1024 * 2;           // 109,051,904
    ushort* wtb    = (ushort*)(w8);                          // 1,572,864
    ushort* offawb = (ushort*)(w8 + 1572864);
    ushort* qb     = (ushort*)(w8 + 1572864 + OASZ);
    ushort* vb     = (ushort*)(w8 + 1572864 + OASZ + SLAB);
    ushort* memb   = (ushort*)(w8 + 1572864 + HSZ);
    ushort* attb   = (ushort*)(w8 + 1572864 + HSZ + SLAB);

    // aliases after death:
    ushort* hidb   = offawb;   // FFN hidden (NTOKP x 1024), overlays offawb+qb+vb
    ushort* bufXb  = memb;     // LN1 out bf16 (memb dead after projs)

    ushort* value_wt = wtb;            // [256][256]
    ushort* offaw_wt = wtb + 65536;    // [384][256]
    ushort* out_wt   = wtb + 163840;   // [256][256]
    ushort* lin1_wt  = wtb + 229376;   // [1024][256]
    ushort* lin2_wt  = wtb + 491520;   // [256][1024]

    const dim3 blk(256);
    const int n4 = NTOK * DMODEL / 4;                       // 3,403,264
    const int prep_total = 2 * n4 + 753664;
    prep_k<<<(prep_total + 255) / 256, blk, 0, stream>>>(
        src, pos, src2, mpos, qb, memb,
        value_w, off_w, aw_w, out_w, lin1_w, lin2_w, wtb, n4);

    const int mt = NTOKP / 64;   // 832 m-strips of 64 rows
    // merged value(2) + offaw(3) projections, n-tile(128) on x
    projs_k<<<dim3(5, mt), blk, 0, stream>>>(memb, qb, value_wt, offaw_wt,
                                             value_b, off_b, aw_b, vb, offawb);

    deform_k<<<dim3(NTOK / 8), blk, 0, stream>>>(vb, offawb, attb);

    // out-proj + residual(src) + LN1 fused -> bufXb bf16
    gemm_ln_k<<<dim3(mt), blk, 0, stream>>>(attb, out_wt, out_b,
                                            src, nullptr, ln_g, ln_b,
                                            nullptr, bufXb, 256);

    // FFN1: hidden bf16 in hidb
    mgemm_k<<<dim3(8, mt), blk, 0, stream>>>(bufXb, lin1_wt, lin1_b, nullptr,
                                             nullptr, hidb, NTOK, DFFN, DMODEL, 1, DFFN);

    // FFN2 + residual(bufXb) + LN2 fused -> d_out f32
    gemm_ln_k<<<dim3(mt), blk, 0, stream>>>(hidb, lin2_wt, lin2_b,
                                            nullptr, bufXb, ln_g, ln_b,
                                            outp, nullptr, 1024);
}

// Round 14
// 359.911 us; speedup vs baseline: 1.0640x; 1.0640x over previous
//
#include <hip/hip_runtime.h>
#include <math.h>

#define L_TOKN 13294
#define BATCHN 4
#define NTOK (BATCHN * L_TOKN)     // 53176
#define NTOKP 53248                // padded: multiple of 128 (and 64)
#define DMODEL 256
#define DFFN 1024

typedef __attribute__((ext_vector_type(8))) short short8;
typedef __attribute__((ext_vector_type(4))) float f32x4;
typedef __attribute__((ext_vector_type(2))) float f32x2;

__device__ __forceinline__ ushort f2b(float f) {
    uint u = __float_as_uint(f);
    u += 0x7fff + ((u >> 16) & 1);
    return (ushort)(u >> 16);
}
__device__ __forceinline__ float b2f(uint h) {
    return __uint_as_float(h << 16);
}

// ---------------------------------------------------------------------------
// prep: [0, 2*n4)  addcvt (qb = bf16(src+pos), memb = bf16(src2+mpos))
//       [2*n4, +753664) weight transpose/convert W[K][N] f32 -> Wt[N][K] bf16
// ---------------------------------------------------------------------------
__global__ __launch_bounds__(256) void prep_k(
    const float* __restrict__ s1, const float* __restrict__ p1,
    const float* __restrict__ s2, const float* __restrict__ p2,
    ushort* __restrict__ o1, ushort* __restrict__ o2,
    const float* __restrict__ w0, const float* __restrict__ w1,
    const float* __restrict__ w2, const float* __restrict__ w3,
    const float* __restrict__ w4, const float* __restrict__ w5,
    ushort* __restrict__ wtb, int n4)
{
    int i = blockIdx.x * 256 + threadIdx.x;
    if (i < 2 * n4) {
        const float* a; const float* b; ushort* o; int j;
        if (i < n4) { a = s1; b = p1; o = o1; j = i; }
        else        { a = s2; b = p2; o = o2; j = i - n4; }
        float4 va = ((const float4*)a)[j];
        float4 vb = ((const float4*)b)[j];
        ushort4 r;
        r.x = f2b(va.x + vb.x); r.y = f2b(va.y + vb.y);
        r.z = f2b(va.z + vb.z); r.w = f2b(va.w + vb.w);
        ((ushort4*)o)[j] = r;
        return;
    }
    int i2 = i - 2 * n4;
    const float* w; int Nd; size_t off; int j;
    if      (i2 < 65536)  { w = w0; Nd = 256;  off = 0;      j = i2; }
    else if (i2 < 131072) { w = w1; Nd = 256;  off = 65536;  j = i2 - 65536; }
    else if (i2 < 163840) { w = w2; Nd = 128;  off = 131072; j = i2 - 131072; }
    else if (i2 < 229376) { w = w3; Nd = 256;  off = 163840; j = i2 - 163840; }
    else if (i2 < 491520) { w = w4; Nd = 1024; off = 229376; j = i2 - 229376; }
    else if (i2 < 753664) { w = w5; Nd = 256;  off = 491520; j = i2 - 491520; }
    else return;
    int Kd = (i2 < 491520) ? 256 : 1024;
    int k = j / Nd, n = j - k * Nd;
    wtb[off + (size_t)n * Kd + k] = f2b(w[j]);
}

// ---------------------------------------------------------------------------
// bf16 MFMA GEMM core, 64x128 tile, BK=32, global_load_lds double-buffered,
// counted vmcnt(3). 24KB LDS -> ~6 blocks/CU. acc[4][2] per wave.
// A rows padded to 64-multiple. Wt[N][K]. NOT safe in-place.
// ---------------------------------------------------------------------------
__device__ __forceinline__ void gemm_core(
    const ushort* __restrict__ A, const ushort* __restrict__ Wt,
    const float* __restrict__ bias, const float* __restrict__ bias2,
    float* __restrict__ Cf, ushort* __restrict__ Cb,
    int M, int N, int K, int relu, int nsplit, int m0, int n0)
{
    __shared__ ushort lds[12288];   // 2 x (A 64x32 + B 128x32) = 24KB

    const int t  = threadIdx.x;
    const int wv = t >> 6, ln_ = t & 63;
    const int fr = ln_ & 15;
    const int kg = ln_ >> 4;

    f32x4 acc[4][2];
    #pragma unroll
    for (int i = 0; i < 4; i++)
        #pragma unroll
        for (int j = 0; j < 2; j++) acc[i][j] = (f32x4)0.0f;

    int aoff[4], boff[2];
    #pragma unroll
    for (int i = 0; i < 4; i++)
        aoff[i] = (i * 16 + fr) * 32 + kg * 8;
    #pragma unroll
    for (int j = 0; j < 2; j++)
        boff[j] = 2048 + (wv * 32 + j * 16 + fr) * 32 + kg * 8;

// 3 loads/thread per STAGE (1 A + 2 B); vmcnt accounting relies on this.
#define STAGE(pbuf, k0) do {                                                       \
    {   /* A: 256 chunks, 1/lane */                                                \
        int c = wv * 64 + ln_;                                                     \
        int m = c >> 2, s = c & 3;                                                 \
        const ushort* sa = A + (size_t)(m0 + m) * K + (k0) + s * 8;                \
        __builtin_amdgcn_global_load_lds(                                          \
            (const __attribute__((address_space(1))) unsigned int*)sa,             \
            (__attribute__((address_space(3))) unsigned int*)&lds[(pbuf) * 6144 + wv * 512], \
            16, 0, 0);                                                             \
    }                                                                              \
    _Pragma("unroll")                                                              \
    for (int ii = 0; ii < 2; ii++) {   /* B: 512 chunks, 2/lane */                 \
        int c = wv * 128 + ii * 64 + ln_;                                          \
        int n = c >> 2, s = c & 3;                                                 \
        const ushort* sb = Wt + (size_t)(n0 + n) * K + (k0) + s * 8;               \
        __builtin_amdgcn_global_load_lds(                                          \
            (const __attribute__((address_space(1))) unsigned int*)sb,             \
            (__attribute__((address_space(3))) unsigned int*)&lds[(pbuf) * 6144 + 2048 + wv * 1024 + ii * 512], \
            16, 0, 0);                                                             \
    }                                                                              \
} while (0)

    const int nk = K >> 5;
    STAGE(0, 0);
    if (nk > 1) STAGE(1, 32);

    for (int ks = 0; ks < nk; ks++) {
        const int p = ks & 1;
        if (ks + 1 < nk) {
            asm volatile("s_waitcnt vmcnt(3)" ::: "memory");
        } else {
            asm volatile("s_waitcnt vmcnt(0)" ::: "memory");
        }
        __builtin_amdgcn_s_barrier();
        __builtin_amdgcn_sched_barrier(0);

        short8 af[4], bf[2];
        const int pb = p * 6144;
        #pragma unroll
        for (int i = 0; i < 4; i++)
            af[i] = *(const short8*)&lds[pb + aoff[i]];
        #pragma unroll
        for (int j = 0; j < 2; j++)
            bf[j] = *(const short8*)&lds[pb + boff[j]];

        if (ks + 2 < nk) {
            asm volatile("s_waitcnt lgkmcnt(0)" ::: "memory");
            __builtin_amdgcn_s_barrier();
            __builtin_amdgcn_sched_barrier(0);
            STAGE(p, (ks + 2) << 5);
        }
        #pragma unroll
        for (int i = 0; i < 4; i++)
            #pragma unroll
            for (int j = 0; j < 2; j++)
                acc[i][j] = __builtin_amdgcn_mfma_f32_16x16x32_bf16(af[i], bf[j], acc[i][j], 0, 0, 0);
    }
#undef STAGE

    #pragma unroll
    for (int i = 0; i < 4; i++) {
        #pragma unroll
        for (int j = 0; j < 2; j++) {
            int col = n0 + wv * 32 + j * 16 + fr;
            float bv = (col < nsplit) ? bias[col] : bias2[col - nsplit];
            #pragma unroll
            for (int e = 0; e < 4; e++) {
                int row = m0 + i * 16 + kg * 4 + e;
                if (row >= M) continue;
                float v = acc[i][j][e] + bv;
                if (relu) v = fmaxf(v, 0.f);
                if (Cf) Cf[(size_t)row * N + col] = v;
                if (Cb) Cb[(size_t)row * N + col] = f2b(v);
            }
        }
    }
}

// bijective XCD swizzle (m204): contiguous tile band per XCD (total % 8 == 0).
__device__ __forceinline__ int2 xcd_tile(int nx)
{
    int flat  = blockIdx.x + blockIdx.y * gridDim.x;
    int total = gridDim.x * gridDim.y;
    int tile;
    if (total & 7) tile = flat;
    else           tile = (flat & 7) * (total >> 3) + (flat >> 3);
    int2 r; r.x = tile % nx; r.y = tile / nx;
    return r;
}

// generic GEMM: n-tile on x (L2 A-reuse), m-strip(64) on y, XCD-swizzled
__global__ __launch_bounds__(256) void mgemm_k(
    const ushort* __restrict__ A, const ushort* __restrict__ Wt,
    const float* __restrict__ bias, const float* __restrict__ bias2,
    float* __restrict__ Cf, ushort* __restrict__ Cb,
    int M, int N, int K, int relu, int nsplit)
{
    int2 xy = xcd_tile(gridDim.x);
    gemm_core(A, Wt, bias, bias2, Cf, Cb, M, N, K, relu, nsplit,
              xy.y * 64, xy.x * 128);
}

// merged value-proj (x<2) + offaw-proj (x>=2), both K=256
__global__ __launch_bounds__(256) void projs_k(
    const ushort* __restrict__ memb, const ushort* __restrict__ qb,
    const ushort* __restrict__ value_wt, const ushort* __restrict__ offaw_wt,
    const float* __restrict__ value_b, const float* __restrict__ off_b,
    const float* __restrict__ aw_b,
    ushort* __restrict__ vb, ushort* __restrict__ offawb)
{
    int2 xy = xcd_tile(5);
    const int x = xy.x;
    const int m0 = xy.y * 64;
    if (x < 2)
        gemm_core(memb, value_wt, value_b, value_b, nullptr, vb,
                  NTOK, 256, 256, 0, 256, m0, x * 128);
    else
        gemm_core(qb, offaw_wt, off_b, aw_b, nullptr, offawb,
                  NTOK, 384, 256, 0, 256, m0, (x - 2) * 128);
}

// ---------------------------------------------------------------------------
// Deformable attention v5: bf16 V (L2-fit), barrier-free, 4 waves x 2 tokens.
// Per point ONE uint4 in LDS: {i00|i10<<16, i01|i11<<16, w00|w10, w01|w11}.
// LDS 17408B -> 8-block wave cap. Phase C: 1 ds_read_b128 per point.
// ---------------------------------------------------------------------------
__global__ __launch_bounds__(256) void deform_k(
    const ushort* __restrict__ Vb,      // bf16 (NTOK,256)
    const ushort* __restrict__ OFFAW,   // bf16 (NTOK,384)
    ushort* __restrict__ OUTb)          // bf16 (NTOK,256)
{
    __shared__ uint4 pw_s[4][2][136];   // 17408 B

    const int t = threadIdx.x;
    const int wv = t >> 6, lane = t & 63;
    const int tok0 = blockIdx.x * 8 + wv * 2;

    const int HWc[4] = {100, 50, 25, 13};
    const int STc[4] = {0, 10000, 12500, 13125};

    const int ppb = lane & 15;
    const int lvb = ppb >> 2;
    #pragma unroll
    for (int it = 0; it < 4; it++) {
        int tk = it >> 1;
        int h  = ((it & 1) << 2) + (lane >> 4);
        int row = tok0 + tk;
        int b = row / L_TOKN;
        int l = row - b * L_TOKN;
        int st_q, Wq;
        if      (l < 10000) { st_q = 0;     Wq = 100; }
        else if (l < 12500) { st_q = 10000; Wq = 50;  }
        else if (l < 13125) { st_q = 12500; Wq = 25;  }
        else                { st_q = 13125; Wq = 13;  }
        int li = l - st_q;
        int rowi = li / Wq;
        int coli = li - rowi * Wq;
        float rx = (coli + 0.5f) / (float)Wq;
        float ry = (rowi + 0.5f) / (float)Wq;

        const size_t rbase = (size_t)row * 384;
        uint oxy = *(const uint*)(OFFAW + rbase + h * 32 + ppb * 2);
        float ox = b2f(oxy & 0xffffu);
        float oy = b2f(oxy >> 16);
        float lg = b2f((uint)OFFAW[rbase + 256 + h * 16 + ppb]);
        float mx = lg;
        #pragma unroll
        for (int o = 8; o; o >>= 1) mx = fmaxf(mx, __shfl_xor(mx, o));
        float ex = __expf(lg - mx);
        float sm = ex;
        #pragma unroll
        for (int o = 8; o; o >>= 1) sm += __shfl_xor(sm, o);
        float aw = ex / sm;

        int Wl = HWc[lvb], stl = STc[lvb];
        float Wlf = (float)Wl;
        float x = (rx + ox / Wlf) * Wlf - 0.5f;
        float y = (ry + oy / Wlf) * Wlf - 0.5f;
        float x0f = floorf(x), y0f = floorf(y);
        float wx1 = x - x0f, wy1 = y - y0f;
        float wx0 = 1.f - wx1, wy0 = 1.f - wy1;
        int x0 = (int)x0f, y0 = (int)y0f;
        bool vx0 = (x0 >= 0) & (x0 < Wl);
        bool vx1 = (x0 + 1 >= 0) & (x0 + 1 < Wl);
        bool vy0 = (y0 >= 0) & (y0 < Wl);
        bool vy1 = (y0 + 1 >= 0) & (y0 + 1 < Wl);
        int cx0 = min(max(x0, 0), Wl - 1), cx1 = min(max(x0 + 1, 0), Wl - 1);
        int cy0 = min(max(y0, 0), Wl - 1), cy1 = min(max(y0 + 1, 0), Wl - 1);
        uint gb = (uint)(b * L_TOKN + stl);
        uint i00 = gb + cy0 * Wl + cx0;
        uint i10 = gb + cy0 * Wl + cx1;
        uint i01 = gb + cy1 * Wl + cx0;
        uint i11 = gb + cy1 * Wl + cx1;
        float w00 = wx0 * wy0 * aw * (float)(vx0 & vy0);
        float w10 = wx1 * wy0 * aw * (float)(vx1 & vy0);
        float w01 = wx0 * wy1 * aw * (float)(vx0 & vy1);
        float w11 = wx1 * wy1 * aw * (float)(vx1 & vy1);
        uint4 pk;
        pk.x = (int)(i00 | (i10 << 16));
        pk.y = (int)(i01 | (i11 << 16));
        pk.z = (int)((uint)f2b(w00) | ((uint)f2b(w10) << 16));
        pk.w = (int)((uint)f2b(w01) | ((uint)f2b(w11) << 16));
        pw_s[wv][tk][h * 17 + ppb] = pk;
    }

    asm volatile("s_waitcnt lgkmcnt(0)" ::: "memory");
    __builtin_amdgcn_sched_barrier(0);

    const int tk = lane >> 5;
    const int h  = (lane >> 2) & 7;
    const int dq = lane & 3;
    const int row = tok0 + tk;
    const uint choff = (uint)(h * 64 + dq * 16);
    const char* __restrict__ vbase = (const char*)Vb;

    f32x2 acc2[4];
    #pragma unroll
    for (int k = 0; k < 4; k++) acc2[k] = (f32x2)0.0f;

    #pragma unroll 8
    for (int pq = 0; pq < 16; pq++) {
        uint4 pk = pw_s[wv][tk][h * 17 + pq];
        float w00 = b2f((uint)pk.z & 0xffffu);
        float w10 = __uint_as_float((uint)pk.z & 0xffff0000u);
        float w01 = b2f((uint)pk.w & 0xffffu);
        float w11 = __uint_as_float((uint)pk.w & 0xffff0000u);
        uint a00 = (((uint)pk.x & 0xffffu) << 9) + choff;
        uint a10 = (((uint)pk.x >> 16) << 9) + choff;
        uint a01 = (((uint)pk.y & 0xffffu) << 9) + choff;
        uint a11 = (((uint)pk.y >> 16) << 9) + choff;
        uint4 v00 = *(const uint4*)(vbase + a00);
        uint4 v10 = *(const uint4*)(vbase + a10);
        uint4 v01 = *(const uint4*)(vbase + a01);
        uint4 v11 = *(const uint4*)(vbase + a11);
        const uint* p00 = (const uint*)&v00;
        const uint* p10 = (const uint*)&v10;
        const uint* p01 = (const uint*)&v01;
        const uint* p11 = (const uint*)&v11;
        #pragma unroll
        for (int k = 0; k < 4; k++) {
            f32x2 a0, a1, a2, a3;
            a0.x = __uint_as_float(p00[k] << 16); a0.y = __uint_as_float(p00[k] & 0xffff0000u);
            a1.x = __uint_as_float(p10[k] << 16); a1.y = __uint_as_float(p10[k] & 0xffff0000u);
            a2.x = __uint_as_float(p01[k] << 16); a2.y = __uint_as_float(p01[k] & 0xffff0000u);
            a3.x = __uint_as_float(p11[k] << 16); a3.y = __uint_as_float(p11[k] & 0xffff0000u);
            acc2[k] += a0 * w00 + a1 * w10 + a2 * w01 + a3 * w11;
        }
    }
    ushort4 olo, ohi;
    olo.x = f2b(acc2[0].x); olo.y = f2b(acc2[0].y);
    olo.z = f2b(acc2[1].x); olo.w = f2b(acc2[1].y);
    ohi.x = f2b(acc2[2].x); ohi.y = f2b(acc2[2].y);
    ohi.z = f2b(acc2[3].x); ohi.w = f2b(acc2[3].y);
    ushort* op = OUTb + (size_t)row * 256 + h * 32 + dq * 8;
    *(ushort4*)op = olo;
    *(ushort4*)(op + 4) = ohi;
}

// ---------------------------------------------------------------------------
// LayerNorm(256), one wave per row.
// ---------------------------------------------------------------------------
__global__ __launch_bounds__(256) void ln_k(
    const float* __restrict__ af, const ushort* __restrict__ ab,
    const float* __restrict__ bf2, const ushort* __restrict__ bb2,
    const float* __restrict__ g, const float* __restrict__ bta,
    float* __restrict__ of, ushort* __restrict__ ob)
{
    const int r = blockIdx.x * 4 + (threadIdx.x >> 6);
    const int lane = threadIdx.x & 63;
    float4 v;
    if (af) {
        v = *((const float4*)(af + (size_t)r * 256) + lane);
    } else {
        ushort4 u = *((const ushort4*)(ab + (size_t)r * 256) + lane);
        v.x = b2f(u.x); v.y = b2f(u.y); v.z = b2f(u.z); v.w = b2f(u.w);
    }
    if (bf2) {
        float4 v2 = *((const float4*)(bf2 + (size_t)r * 256) + lane);
        v.x += v2.x; v.y += v2.y; v.z += v2.z; v.w += v2.w;
    } else if (bb2) {
        ushort4 u = *((const ushort4*)(bb2 + (size_t)r * 256) + lane);
        v.x += b2f(u.x); v.y += b2f(u.y); v.z += b2f(u.z); v.w += b2f(u.w);
    }
    float s = v.x + v.y + v.z + v.w;
    #pragma unroll
    for (int o = 32; o; o >>= 1) s += __shfl_xor(s, o);
    float mu = s * (1.f / 256.f);
    float4 d; d.x = v.x - mu; d.y = v.y - mu; d.z = v.z - mu; d.w = v.w - mu;
    float s2 = d.x * d.x + d.y * d.y + d.z * d.z + d.w * d.w;
    #pragma unroll
    for (int o = 32; o; o >>= 1) s2 += __shfl_xor(s2, o);
    float rstd = rsqrtf(s2 * (1.f / 256.f) + 1e-5f);
    float4 gg = ((const float4*)g)[lane];
    float4 bb = ((const float4*)bta)[lane];
    float4 out;
    out.x = d.x * rstd * gg.x + bb.x;
    out.y = d.y * rstd * gg.y + bb.y;
    out.z = d.z * rstd * gg.z + bb.z;
    out.w = d.w * rstd * gg.w + bb.w;
    if (of) *((float4*)(of + (size_t)r * 256) + lane) = out;
    if (ob) {
        ushort4 o4;
        o4.x = f2b(out.x); o4.y = f2b(out.y); o4.z = f2b(out.z); o4.w = f2b(out.w);
        *((ushort4*)(ob + (size_t)r * 256) + lane) = o4;
    }
}

// ---------------------------------------------------------------------------
extern "C" void kernel_launch(void* const* d_in, const int* in_sizes, int n_in,
                              void* d_out, int out_size, void* d_ws, size_t ws_size,
                              hipStream_t stream)
{
    const float* src     = (const float*)d_in[0];
    const float* src2    = (const float*)d_in[1];
    const float* pos     = (const float*)d_in[2];
    const float* mpos    = (const float*)d_in[3];
    const float* value_w = (const float*)d_in[4];
    const float* value_b = (const float*)d_in[5];
    const float* off_w   = (const float*)d_in[6];
    const float* off_b   = (const float*)d_in[7];
    const float* aw_w    = (const float*)d_in[8];
    const float* aw_b    = (const float*)d_in[9];
    const float* out_w   = (const float*)d_in[10];
    const float* out_b   = (const float*)d_in[11];
    const float* ln_g    = (const float*)d_in[12];
    const float* ln_b    = (const float*)d_in[13];
    const float* lin1_w  = (const float*)d_in[14];
    const float* lin1_b  = (const float*)d_in[15];
    const float* lin2_w  = (const float*)d_in[16];
    const float* lin2_b  = (const float*)d_in[17];

    float* outp = (float*)d_out;
    char*  w8   = (char*)d_ws;

    // layout (bytes): wtb | offawb | qb | vb | pad | memb | attb
    // hidden (109,051,904) overlays offawb+qb+vb+pad exactly.
    const size_t SLAB = (size_t)NTOKP * 256 * 2;            // 27,262,976
    const size_t OASZ = (size_t)NTOKP * 384 * 2;            // 40,894,464
    const size_t HSZ  = (size_t)NTOKP * 1024 * 2;           // 109,051,904
    ushort* wtb    = (ushort*)(w8);                          // 1,572,864
    ushort* offawb = (ushort*)(w8 + 1572864);
    ushort* qb     = (ushort*)(w8 + 1572864 + OASZ);
    ushort* vb     = (ushort*)(w8 + 1572864 + OASZ + SLAB);
    ushort* memb   = (ushort*)(w8 + 1572864 + HSZ);
    ushort* attb   = (ushort*)(w8 + 1572864 + HSZ + SLAB);

    // aliases after death:
    ushort* hidb   = offawb;   // FFN hidden (NTOKP x 1024), overlays offawb+qb+vb
    ushort* bufXb  = memb;     // LN1 out bf16 (memb dead after projs)
    ushort* projb  = vb;       // out-proj result (vb dead after deform)
    ushort* ffn2b  = attb;     // FFN2 bf16 out (attb dead after out-proj)

    ushort* value_wt = wtb;            // [256][256]
    ushort* offaw_wt = wtb + 65536;    // [384][256]
    ushort* out_wt   = wtb + 163840;   // [256][256]
    ushort* lin1_wt  = wtb + 229376;   // [1024][256]
    ushort* lin2_wt  = wtb + 491520;   // [256][1024]

    const dim3 blk(256);
    const int n4 = NTOK * DMODEL / 4;                       // 3,403,264
    const int prep_total = 2 * n4 + 753664;
    prep_k<<<(prep_total + 255) / 256, blk, 0, stream>>>(
        src, pos, src2, mpos, qb, memb,
        value_w, off_w, aw_w, out_w, lin1_w, lin2_w, wtb, n4);

    const int mt = NTOKP / 64;   // 832 m-strips of 64 rows
    // merged value(2) + offaw(3) projections, n-tile(128) on x
    projs_k<<<dim3(5, mt), blk, 0, stream>>>(memb, qb, value_wt, offaw_wt,
                                             value_b, off_b, aw_b, vb, offawb);

    deform_k<<<dim3(NTOK / 8), blk, 0, stream>>>(vb, offawb, attb);

    // out proj: attb -> projb
    mgemm_k<<<dim3(2, mt), blk, 0, stream>>>(attb, out_wt, out_b, nullptr,
                                             nullptr, projb, NTOK, 256, 256, 0, 256);
    // x = LN(attn_proj + src) -> bufXb bf16
    ln_k<<<dim3(NTOK / 4), blk, 0, stream>>>(nullptr, projb, src, nullptr,
                                             ln_g, ln_b, nullptr, bufXb);

    // FFN single-chunk: hidden bf16 in hidb; FFN2 -> ffn2b bf16
    mgemm_k<<<dim3(8, mt), blk, 0, stream>>>(bufXb, lin1_wt, lin1_b, nullptr,
                                             nullptr, hidb, NTOK, DFFN, DMODEL, 1, DFFN);
    mgemm_k<<<dim3(2, mt), blk, 0, stream>>>(hidb, lin2_wt, lin2_b, nullptr,
                                             nullptr, ffn2b, NTOK, DMODEL, DFFN, 0, DMODEL);

    // out = LN(ffn + x) -> d_out f32
    ln_k<<<dim3(NTOK / 4), blk, 0, stream>>>(nullptr, ffn2b, nullptr, bufXb,
                                             ln_g, ln_b, outp, nullptr);
}